// Round 2
// baseline (121.660 us; speedup 1.0000x reference)
//
#include <hip/hip_runtime.h>

// Embedding-bag: out[b,:] = bias + sum_k vals[b,k] * weight[ics[b,k],:]
// B=16384, K=32, N_OUT=256.
//
// - 8 column-slices of 32 cols; slice = blockIdx % 8 -> XCD round-robin,
//   per-XCD gather slab = 41024*32*4B = 5.25 MiB (~81-90% L2 hit).
// - Wave = 8 rows x 8 lanes (float4 each); indices int4-prefetched and
//   broadcast via __shfl; padding masked branchlessly.
// - R3: VGPR=36 proved the compiler sank the wv[8] batch to ~2-4 loads in
//   flight (8xfloat4 alone = 32 VGPRs). Force 16-in-flight via inline-asm
//   global_load_dwordx4 + double-buffered s_waitcnt vmcnt(8) pipeline.
//   sched_barrier(0) after each waitcnt: hipcc hoists register-only
//   consumers past inline-asm waitcnts otherwise.
// - nontemporal store for out (via ext_vector f32x4 — HIP float4 class is
//   rejected by the builtin): stop the 16 MB output stream from evicting
//   the weight slab in L2.

constexpr int K = 32;

typedef float f32x4 __attribute__((ext_vector_type(4)));

__global__ __launch_bounds__(256) void FeatureTransformer_45896020525219_kernel(
    const int* __restrict__ ics,
    const float* __restrict__ vals,
    const f32x4* __restrict__ w4,      // [N_IN * 64]
    const f32x4* __restrict__ bias4,   // [64]
    f32x4* __restrict__ out4,          // [B * 64]
    int B)
{
    const int lane   = threadIdx.x & 63;
    const int wave   = threadIdx.x >> 6;
    const int slice  = blockIdx.x & 7;   // -> XCD (locality heuristic)
    const int rowblk = blockIdx.x >> 3;

    const int r  = lane >> 3;            // local row 0..7
    const int c4 = lane & 7;             // float4-column within the 32-col slice
    const int b  = rowblk * 32 + wave * 8 + r;
    if (b >= B) return;

    const int colbase = slice * 8 + c4;  // float4 index within the 64 per row

    // Lane holds k-quad c4 of its row's indices/values (coalesced 128B/row).
    const int4   idx4 = ((const int4*)  (ics  + b * K))[c4];
    const float4 v4   = ((const float4*)(vals + b * K))[c4];

    f32x4 acc;
    {
        f32x4 bb = bias4[colbase];
        acc = bb;
    }

    const f32x4* wbase = w4 + colbase;

    f32x4 wva[8], wvb[8];
    float vva[8], vvb[8];

    // Issue 8 independent gathers for chunk c into (wvd, vvd).
    // asm volatile loads stay in program order relative to the waitcnt asm,
    // guaranteeing 8 loads actually in flight per chunk (16 across 2 chunks).
    auto issue = [&](const int c, f32x4* wvd, float* vvd) {
        #pragma unroll
        for (int u = 0; u < 8; ++u) {
            const int k   = c * 8 + u;
            const int src = (lane & 56) | (k >> 2);  // lane in row-group holding k
            const int sel = k & 3;                   // compile-time constant
            const int   jc = sel == 0 ? idx4.x : sel == 1 ? idx4.y
                           : sel == 2 ? idx4.z : idx4.w;
            const float vc = sel == 0 ? v4.x   : sel == 1 ? v4.y
                           : sel == 2 ? v4.z   : v4.w;
            const int   jj = __shfl(jc, src);
            const float vs = __shfl(vc, src);

            vvd[u] = (jj >= 0) ? vs : 0.0f;          // branchless padding
            const unsigned j = (jj >= 0) ? (unsigned)jj : 0u;
            const f32x4* p  = wbase + (size_t)j * 64;
            asm volatile("global_load_dwordx4 %0, %1, off"
                         : "=v"(wvd[u]) : "v"(p));
        }
    };

    auto dofma = [&](const f32x4* wvd, const float* vvd) {
        #pragma unroll
        for (int u = 0; u < 8; ++u) {
            acc.x = fmaf(vvd[u], wvd[u].x, acc.x);
            acc.y = fmaf(vvd[u], wvd[u].y, acc.y);
            acc.z = fmaf(vvd[u], wvd[u].z, acc.z);
            acc.w = fmaf(vvd[u], wvd[u].w, acc.w);
        }
    };

    issue(0, wva, vva);
    issue(1, wvb, vvb);

    asm volatile("s_waitcnt vmcnt(8)" ::: "memory");  // chunk 0 complete
    __builtin_amdgcn_sched_barrier(0);
    dofma(wva, vva);
    issue(2, wva, vva);

    asm volatile("s_waitcnt vmcnt(8)" ::: "memory");  // chunk 1 complete
    __builtin_amdgcn_sched_barrier(0);
    dofma(wvb, vvb);
    issue(3, wvb, vvb);

    asm volatile("s_waitcnt vmcnt(8)" ::: "memory");  // chunk 2 complete
    __builtin_amdgcn_sched_barrier(0);
    dofma(wva, vva);

    asm volatile("s_waitcnt vmcnt(0)" ::: "memory");  // chunk 3 complete
    __builtin_amdgcn_sched_barrier(0);
    dofma(wvb, vvb);

    __builtin_nontemporal_store(acc, (f32x4*)(out4 + (size_t)b * 64 + colbase));
}

extern "C" void kernel_launch(void* const* d_in, const int* in_sizes, int n_in,
                              void* d_out, int out_size, void* d_ws, size_t ws_size,
                              hipStream_t stream) {
    const int*   ics   = (const int*)d_in[0];
    const float* vals  = (const float*)d_in[1];
    const f32x4* w4    = (const f32x4*)d_in[2];
    const f32x4* bias4 = (const f32x4*)d_in[3];
    f32x4*       out4  = (f32x4*)d_out;

    const int B = in_sizes[0] / K;            // 16384
    const int blocks = ((B + 31) / 32) * 8;   // 32 rows/block x 8 slices = 4096

    hipLaunchKernelGGL(FeatureTransformer_45896020525219_kernel,
                       dim3(blocks), dim3(256), 0, stream,
                       ics, vals, w4, bias4, out4, B);
}